// Round 1
// baseline (1598.711 us; speedup 1.0000x reference)
//
#include <hip/hip_runtime.h>
#include <math.h>

#define H 192
#define W 192
#define CIN 32
#define COUT 64
#define BATCH 16

// ConvTranspose2d(32->64, k3, s1, p1) + bias + MaxPool2x2 + Hardtanh + partial
// spatial sum per (b, co). Each block: one (row-chunk, co, b).
// 192 threads: thread tile = 4 conv rows x 8 conv cols = 2x4 pooled outputs.
// ct = tid>>3 (24 col tiles), rt = tid&7 (8 row tiles) -> 32 conv rows/chunk.
__global__ __launch_bounds__(192)
void conv_pool_partial(const float* __restrict__ x,
                       const float* __restrict__ weight,
                       const float* __restrict__ bias,
                       float* __restrict__ accum) {
  const int chunk = blockIdx.x;   // 0..5   (6 * 32 = 192 rows)
  const int co    = blockIdx.y;   // 0..63
  const int b     = blockIdx.z;   // 0..15
  const int tid   = threadIdx.x;
  const int ct    = tid >> 3;     // 0..23  col tile (8 cols each)
  const int rt    = tid & 7;      // 0..7   row tile (4 rows each)
  const int r0    = chunk * 32 + rt * 4;
  const int c0    = ct * 8;

  const float* xb = x + (size_t)b * CIN * H * W;

  float acc[4][8];
  #pragma unroll
  for (int i = 0; i < 4; ++i)
    #pragma unroll
    for (int j = 0; j < 8; ++j) acc[i][j] = 0.f;

  const bool rv0 = (r0 - 1) >= 0;   // top halo row exists
  const bool rv5 = (r0 + 4) < H;    // bottom halo row exists
  const bool cv0 = (c0 - 1) >= 0;   // left halo col exists
  const bool cv9 = (c0 + 8) < W;    // right halo col exists

  for (int ci = 0; ci < CIN; ++ci) {
    // Flipped weights for this (ci, co) — uniform across block -> SGPRs.
    float wf[3][3];
    #pragma unroll
    for (int a = 0; a < 3; ++a)
      #pragma unroll
      for (int d = 0; d < 3; ++d)
        wf[a][d] = weight[((ci * COUT + co) * 3 + (2 - a)) * 3 + (2 - d)];

    const float* xp = xb + (size_t)ci * H * W;

    // x patch: rows r0-1 .. r0+4 (6), cols c0-1 .. c0+8 (10)
    float xr[6][10];
    #pragma unroll
    for (int k = 0; k < 6; ++k) {
      const int r  = r0 - 1 + k;
      const int rc = r < 0 ? 0 : (r >= H ? H - 1 : r);
      const float* rp = xp + rc * W;
      const float4 m = *(const float4*)(rp + c0);
      const float4 n = *(const float4*)(rp + c0 + 4);
      const float lo = rp[cv0 ? c0 - 1 : 0];
      const float hi = rp[cv9 ? c0 + 8 : W - 1];
      const bool rv = (k == 0) ? rv0 : ((k == 5) ? rv5 : true);
      xr[k][0] = (rv && cv0) ? lo  : 0.f;
      xr[k][1] = rv ? m.x : 0.f;
      xr[k][2] = rv ? m.y : 0.f;
      xr[k][3] = rv ? m.z : 0.f;
      xr[k][4] = rv ? m.w : 0.f;
      xr[k][5] = rv ? n.x : 0.f;
      xr[k][6] = rv ? n.y : 0.f;
      xr[k][7] = rv ? n.z : 0.f;
      xr[k][8] = rv ? n.w : 0.f;
      xr[k][9] = (rv && cv9) ? hi : 0.f;
    }

    // 288 FMAs: acc[i][j] += xr[i+a][j+d] * wf[a][d]
    #pragma unroll
    for (int i = 0; i < 4; ++i)
      #pragma unroll
      for (int a = 0; a < 3; ++a)
        #pragma unroll
        for (int j = 0; j < 8; ++j)
          #pragma unroll
          for (int d = 0; d < 3; ++d)
            acc[i][j] = fmaf(xr[i + a][j + d], wf[a][d], acc[i][j]);
  }

  // bias + maxpool 2x2 + hardtanh + partial sum (8 pooled vals per thread)
  const float bv = bias[co];
  float part = 0.f;
  #pragma unroll
  for (int i = 0; i < 2; ++i)
    #pragma unroll
    for (int j = 0; j < 4; ++j) {
      float v = fmaxf(fmaxf(acc[2 * i][2 * j], acc[2 * i][2 * j + 1]),
                      fmaxf(acc[2 * i + 1][2 * j], acc[2 * i + 1][2 * j + 1]));
      v += bv;
      v = fminf(fmaxf(v, -1.f), 1.f);
      part += v;
    }

  // wave (64-lane) shuffle reduce, then cross-wave via LDS
  #pragma unroll
  for (int off = 32; off > 0; off >>= 1)
    part += __shfl_down(part, off, 64);

  __shared__ float wsum[3];
  const int wid  = tid >> 6;
  const int lane = tid & 63;
  if (lane == 0) wsum[wid] = part;
  __syncthreads();
  if (tid == 0)
    atomicAdd(&accum[b * COUT + co], wsum[0] + wsum[1] + wsum[2]);
}

__global__ void finish_kernel(const float* __restrict__ accum,
                              float* __restrict__ out, int n) {
  const int i = blockIdx.x * blockDim.x + threadIdx.x;
  if (i < n) out[i] = tanhf(accum[i] * (1.0f / (96.0f * 96.0f)));
}

extern "C" void kernel_launch(void* const* d_in, const int* in_sizes, int n_in,
                              void* d_out, int out_size, void* d_ws, size_t ws_size,
                              hipStream_t stream) {
  const float* x      = (const float*)d_in[0];
  const float* weight = (const float*)d_in[1];
  const float* bias   = (const float*)d_in[2];
  float* out = (float*)d_out;
  float* ws  = (float*)d_ws;

  // ws is re-poisoned 0xAA before every launch — zero the accumulators.
  hipMemsetAsync(ws, 0, BATCH * COUT * sizeof(float), stream);

  dim3 grid(6, COUT, BATCH);
  conv_pool_partial<<<grid, 192, 0, stream>>>(x, weight, bias, ws);

  const int n = BATCH * COUT;
  finish_kernel<<<(n + 255) / 256, 256, 0, stream>>>(ws, out, n);
}

// Round 2
// 180.055 us; speedup vs baseline: 8.8790x; 8.8790x over previous
//
#include <hip/hip_runtime.h>
#include <hip/hip_bf16.h>
#include <math.h>

#define H 192
#define W 192
#define CIN 32
#define COUT 64
#define BATCH 16

// Padded, channel-minor bf16 copy of x: x_t[b][194][194][32], zero border.
#define HP 194
#define XT_ELEMS ((size_t)BATCH * HP * HP * CIN)            // 19,269,632
#define XT_BYTES (XT_ELEMS * 2)                              // 38,539,264
#define WP_OFF   XT_BYTES                                    // 9*64*32 bf16
#define WP_BYTES ((size_t)9 * COUT * CIN * 2)                // 36,864
#define ACC_OFF  (WP_OFF + WP_BYTES)                         // 1024 f32
#define ACC_BYTES ((size_t)BATCH * COUT * 4)
#define WS_NEED  (ACC_OFF + ACC_BYTES)

typedef __attribute__((ext_vector_type(8)))  short bf16x8;
typedef __attribute__((ext_vector_type(16))) float f32x16;

static __device__ __forceinline__ short f2bf(float f) {
  __hip_bfloat16 h = __float2bfloat16(f);
  return __builtin_bit_cast(short, h);
}

// ---------------- pre-pass 1: x [b][ci][h][w] f32 -> x_t [b][h+1][w+1][ci] bf16
__global__ __launch_bounds__(192)
void transpose_pack(const float* __restrict__ x, short* __restrict__ xt) {
  const int w = threadIdx.x;        // 0..191
  const int h = blockIdx.x;         // 0..191
  const int b = blockIdx.y;         // 0..15
  const float* px = x + (((size_t)b * CIN) * H + h) * W + w;  // x[b][0][h][w]
  short* dst = xt + (((size_t)b * HP + h + 1) * HP + (w + 1)) * CIN;
  #pragma unroll
  for (int q = 0; q < 4; ++q) {
    bf16x8 o;
    #pragma unroll
    for (int j = 0; j < 8; ++j)
      o[j] = f2bf(px[(size_t)(q * 8 + j) * (H * W)]);
    *(bf16x8*)(dst + q * 8) = o;
  }
}

// ---------------- pre-pass 2: weight [ci][co][kh][kw] f32 -> Wp[tap][co][ci] bf16
// Wp[a*3+d][co][ci] = weight[ci][co][2-a][2-d]  (flipped kernel)
__global__ void pack_weights(const float* __restrict__ wsrc, short* __restrict__ wp) {
  const int idx = blockIdx.x * 256 + threadIdx.x;
  if (idx >= 9 * COUT * CIN) return;
  const int ci  = idx & 31;
  const int co  = (idx >> 5) & 63;
  const int tap = idx >> 11;
  const int a = tap / 3, d = tap % 3;
  wp[idx] = f2bf(wsrc[((ci * COUT + co) * 3 + (2 - a)) * 3 + (2 - d)]);
}

// ---------------- main: implicit GEMM + fused maxpool/hardtanh/partial-sum
// grid (96 h-pairs, 16 b), 256 threads = 4 waves:
//   wave&1  -> co tile (0 or 32),  wave>>1 -> w half (0..95 / 96..191)
// Per wave: 3 w-tiles of 32 pixels; per tile 2 conv rows (h0,h0+1) x 32 co.
__global__ __launch_bounds__(256)
void conv_pool_gemm(const short* __restrict__ xt, const short* __restrict__ wp,
                    const float* __restrict__ bias, float* __restrict__ accum) {
  const int hp   = blockIdx.x;           // 0..95
  const int b    = blockIdx.y;           // 0..15
  const int tid  = threadIdx.x;
  const int wave = tid >> 6;
  const int l    = tid & 63;
  const int co0  = (wave & 1) * 32;
  const int wh   = wave >> 1;
  const int l31  = l & 31;
  const int kg   = (l >> 5) * 8;         // k-subgroup within 16

  // B fragments: 9 taps x 2 ci-halves, 16B/lane, kept in registers.
  bf16x8 bw[9][2];
  {
    const short* p = wp + (co0 + l31) * 32 + kg;
    #pragma unroll
    for (int tap = 0; tap < 9; ++tap)
      #pragma unroll
      for (int hf = 0; hf < 2; ++hf)
        bw[tap][hf] = *(const bf16x8*)(p + tap * 2048 + hf * 16);
  }

  const int h0 = hp * 2;
  const float bv = bias[co0 + l31];
  float sum = 0.f;

  for (int wt = 0; wt < 3; ++wt) {
    const int w0 = wh * 96 + wt * 32;
    f32x16 acc0, acc1;
    #pragma unroll
    for (int i = 0; i < 16; ++i) { acc0[i] = 0.f; acc1[i] = 0.f; }

    // x_t rows h0..h0+3 feed conv rows h0 (a=xr) and h0+1 (a=xr-1).
    #pragma unroll
    for (int xr = 0; xr < 4; ++xr) {
      const short* rp = xt + (((size_t)b * HP + h0 + xr) * HP + w0 + l31) * CIN + kg;
      #pragma unroll
      for (int d = 0; d < 3; ++d) {
        #pragma unroll
        for (int hf = 0; hf < 2; ++hf) {
          const bf16x8 af = *(const bf16x8*)(rp + d * CIN + hf * 16);
          if (xr < 3)
            acc0 = __builtin_amdgcn_mfma_f32_32x32x16_bf16(af, bw[xr * 3 + d][hf], acc0, 0, 0, 0);
          if (xr > 0)
            acc1 = __builtin_amdgcn_mfma_f32_32x32x16_bf16(af, bw[(xr - 1) * 3 + d][hf], acc1, 0, 0, 0);
        }
      }
    }

    // Epilogue: C row = (reg&3) + 8*(reg>>2) + 4*(l>>5); regs (2g,2g+1) are a
    // w-pair, acc0/acc1 are the h-pair -> 2x2 maxpool entirely in-lane.
    #pragma unroll
    for (int g = 0; g < 8; ++g) {
      float m = fmaxf(fmaxf(acc0[2 * g], acc0[2 * g + 1]),
                      fmaxf(acc1[2 * g], acc1[2 * g + 1]));
      float v = m + bv;
      v = fminf(fmaxf(v, -1.f), 1.f);
      sum += v;
    }
  }

  // lanes l and l^32 hold the same co, different pixel groups
  sum += __shfl_xor(sum, 32, 64);
  if (l < 32) atomicAdd(&accum[b * COUT + co0 + l31], sum);
}

__global__ void finish_kernel(const float* __restrict__ accum,
                              float* __restrict__ out, int n) {
  const int i = blockIdx.x * blockDim.x + threadIdx.x;
  if (i < n) out[i] = tanhf(accum[i] * (1.0f / (96.0f * 96.0f)));
}

// ---------------- fallback (round-1 fp32 kernel) if ws is too small ----------
__global__ __launch_bounds__(192)
void conv_pool_partial(const float* __restrict__ x, const float* __restrict__ weight,
                       const float* __restrict__ bias, float* __restrict__ accum) {
  const int chunk = blockIdx.x, co = blockIdx.y, b = blockIdx.z;
  const int tid = threadIdx.x;
  const int ct = tid >> 3, rt = tid & 7;
  const int r0 = chunk * 32 + rt * 4, c0 = ct * 8;
  const float* xb = x + (size_t)b * CIN * H * W;
  float acc[4][8];
  #pragma unroll
  for (int i = 0; i < 4; ++i)
    #pragma unroll
    for (int j = 0; j < 8; ++j) acc[i][j] = 0.f;
  const bool rv0 = (r0 - 1) >= 0, rv5 = (r0 + 4) < H;
  const bool cv0 = (c0 - 1) >= 0, cv9 = (c0 + 8) < W;
  for (int ci = 0; ci < CIN; ++ci) {
    float wf[3][3];
    #pragma unroll
    for (int a = 0; a < 3; ++a)
      #pragma unroll
      for (int d = 0; d < 3; ++d)
        wf[a][d] = weight[((ci * COUT + co) * 3 + (2 - a)) * 3 + (2 - d)];
    const float* xp = xb + (size_t)ci * H * W;
    float xr[6][10];
    #pragma unroll
    for (int k = 0; k < 6; ++k) {
      const int r = r0 - 1 + k;
      const int rc = r < 0 ? 0 : (r >= H ? H - 1 : r);
      const float* rp = xp + rc * W;
      const float4 m = *(const float4*)(rp + c0);
      const float4 n = *(const float4*)(rp + c0 + 4);
      const float lo = rp[cv0 ? c0 - 1 : 0];
      const float hi = rp[cv9 ? c0 + 8 : W - 1];
      const bool rv = (k == 0) ? rv0 : ((k == 5) ? rv5 : true);
      xr[k][0] = (rv && cv0) ? lo : 0.f;
      xr[k][1] = rv ? m.x : 0.f; xr[k][2] = rv ? m.y : 0.f;
      xr[k][3] = rv ? m.z : 0.f; xr[k][4] = rv ? m.w : 0.f;
      xr[k][5] = rv ? n.x : 0.f; xr[k][6] = rv ? n.y : 0.f;
      xr[k][7] = rv ? n.z : 0.f; xr[k][8] = rv ? n.w : 0.f;
      xr[k][9] = (rv && cv9) ? hi : 0.f;
    }
    #pragma unroll
    for (int i = 0; i < 4; ++i)
      #pragma unroll
      for (int a = 0; a < 3; ++a)
        #pragma unroll
        for (int j = 0; j < 8; ++j)
          #pragma unroll
          for (int d = 0; d < 3; ++d)
            acc[i][j] = fmaf(xr[i + a][j + d], wf[a][d], acc[i][j]);
  }
  const float bv = bias[co];
  float part = 0.f;
  #pragma unroll
  for (int i = 0; i < 2; ++i)
    #pragma unroll
    for (int j = 0; j < 4; ++j) {
      float v = fmaxf(fmaxf(acc[2 * i][2 * j], acc[2 * i][2 * j + 1]),
                      fmaxf(acc[2 * i + 1][2 * j], acc[2 * i + 1][2 * j + 1]));
      v += bv;
      part += fminf(fmaxf(v, -1.f), 1.f);
    }
  #pragma unroll
  for (int off = 32; off > 0; off >>= 1) part += __shfl_down(part, off, 64);
  __shared__ float wsum[3];
  const int wid = tid >> 6, lane = tid & 63;
  if (lane == 0) wsum[wid] = part;
  __syncthreads();
  if (tid == 0) atomicAdd(&accum[b * COUT + co], wsum[0] + wsum[1] + wsum[2]);
}

extern "C" void kernel_launch(void* const* d_in, const int* in_sizes, int n_in,
                              void* d_out, int out_size, void* d_ws, size_t ws_size,
                              hipStream_t stream) {
  const float* x      = (const float*)d_in[0];
  const float* weight = (const float*)d_in[1];
  const float* bias   = (const float*)d_in[2];
  float* out = (float*)d_out;

  if (ws_size >= WS_NEED) {
    short* xt = (short*)d_ws;
    short* wp = (short*)((char*)d_ws + WP_OFF);
    float* accum = (float*)((char*)d_ws + ACC_OFF);
    hipMemsetAsync(d_ws, 0, XT_BYTES, stream);                    // zero-padded x_t
    hipMemsetAsync(accum, 0, ACC_BYTES, stream);
    pack_weights<<<dim3((9 * COUT * CIN + 255) / 256), 256, 0, stream>>>(weight, wp);
    transpose_pack<<<dim3(H, BATCH), 192, 0, stream>>>(x, xt);
    conv_pool_gemm<<<dim3(96, BATCH), 256, 0, stream>>>(xt, wp, bias, accum);
    finish_kernel<<<dim3((BATCH * COUT + 255) / 256), 256, 0, stream>>>(
        accum, out, BATCH * COUT);
  } else {
    float* accum = (float*)d_ws;
    hipMemsetAsync(accum, 0, ACC_BYTES, stream);
    conv_pool_partial<<<dim3(6, COUT, BATCH), 192, 0, stream>>>(x, weight, bias, accum);
    finish_kernel<<<dim3((BATCH * COUT + 255) / 256), 256, 0, stream>>>(
        accum, out, BATCH * COUT);
  }
}